// Round 9
// baseline (212.335 us; speedup 1.0000x reference)
//
#include <hip/hip_runtime.h>

#define D 128
#define NSEG 2048
#define EPSV 1e-6f
#define BLOCK 512
#define QCH 8            // f32x4 chunks per row per tile (32 cols, 128 B slice)
#define NQ 4             // column splits per segment
#define CPRF 32          // f32x4 chunks per full row
#define RG (BLOCK/QCH)   // 64 row-groups
#define WAVES (BLOCK/64) // 8
#define MAXK 8           // buffered slots/thread: MAXK*RG = 512 rows
#define TILES 16         // tiles per persistent block
#define NBLK (NSEG*NQ/TILES)  // 512 persistent blocks (2/CU resident)

typedef float f32x4 __attribute__((ext_vector_type(4)));

// Tiny kernel: segment bounds (lower_bound for 0..NSEG) into d_ws.
__global__ void seg_bounds(const int* __restrict__ seg, int* __restrict__ offs, int N) {
    const int i = blockIdx.x * blockDim.x + threadIdx.x;
    if (i <= NSEG) {
        int lo = 0, hi = N;
        while (lo < hi) {
            int mid = (lo + hi) >> 1;
            if (seg[mid] < i) lo = mid + 1; else hi = mid;
        }
        offs[i] = lo;
    }
}

// Persistent blocks, register double-buffer, raw barrier (lgkmcnt-only drain).
// Stage tile i+1 BEFORE consuming tile i; loads stay in flight across the
// per-tile barrier (no vmcnt(0) drain -> HBM read stream never starves).
__global__ __launch_bounds__(BLOCK, 4) void graphnorm_persist(
    const float* __restrict__ feat,
    const int* __restrict__ offs,
    const float* __restrict__ weight,
    const float* __restrict__ bias,
    const float* __restrict__ mean_scale,
    float* __restrict__ out)
{
    const int t = threadIdx.x;
    const int c    = t & (QCH - 1);   // chunk within slice 0..7
    const int g    = t >> 3;          // row group 0..63
    const int w    = t >> 6;          // wave 0..7
    const int lane = t & 63;

    // parity-indexed partials: no second barrier needed per tile
    __shared__ f32x4 p_sum[2][WAVES][QCH];
    __shared__ f32x4 p_sq[2][WAVES][QCH];

    const f32x4* feat4 = reinterpret_cast<const f32x4*>(feat);
    f32x4* out4 = reinterpret_cast<f32x4*>(out);
    const int base = blockIdx.x * TILES;

    f32x4 bufA[MAXK], bufB[MAXK];
    int stA, enA, chA, stB, enB, chB;

#define TILEINFO(TI, ST, EN, CH)                 \
    {                                            \
        const int s_ = (TI) >> 2;                \
        ST = offs[s_];                           \
        EN = offs[s_ + 1];                       \
        CH = ((TI) & 3) * QCH + c;               \
    }

#define STAGE(BUF, ST, EN, CH)                           \
    _Pragma("unroll")                                    \
    for (int k = 0; k < MAXK; ++k) {                     \
        const int r = ST + g + k * RG;                   \
        if (r < EN) BUF[k] = feat4[r * CPRF + CH];       \
    }

#define CONSUME(BUF, ST, EN, CH, P)                                        \
    {                                                                      \
        f32x4 s0 = 0.f, q0 = 0.f;                                          \
        _Pragma("unroll")                                                  \
        for (int k = 0; k < MAXK; ++k) {                                   \
            const int r = ST + g + k * RG;                                 \
            if (r < EN) { s0 += BUF[k]; q0 += BUF[k] * BUF[k]; }           \
        }                                                                  \
        const int tail_base = ST + g + MAXK * RG;                          \
        for (int r = tail_base; r < EN; r += RG) {                         \
            f32x4 v = feat4[r * CPRF + CH];                                \
            s0 += v; q0 += v * v;                                          \
        }                                                                  \
        _Pragma("unroll")                                                  \
        for (int i = 0; i < 4; ++i) {                                      \
            s0[i] += __shfl_xor(s0[i], 8);                                 \
            s0[i] += __shfl_xor(s0[i], 16);                                \
            s0[i] += __shfl_xor(s0[i], 32);                                \
            q0[i] += __shfl_xor(q0[i], 8);                                 \
            q0[i] += __shfl_xor(q0[i], 16);                                \
            q0[i] += __shfl_xor(q0[i], 32);                                \
        }                                                                  \
        if (lane < QCH) {                                                  \
            p_sum[P][w][lane] = s0;                                        \
            p_sq[P][w][lane]  = q0;                                        \
        }                                                                  \
        asm volatile("s_waitcnt lgkmcnt(0)" ::: "memory");                 \
        __builtin_amdgcn_s_barrier();                                      \
        __builtin_amdgcn_sched_barrier(0);                                 \
        f32x4 sm = p_sum[P][0][c];                                         \
        f32x4 sg = p_sq[P][0][c];                                          \
        _Pragma("unroll")                                                  \
        for (int i = 1; i < WAVES; ++i) {                                  \
            sm += p_sum[P][i][c];                                          \
            sg += p_sq[P][i][c];                                           \
        }                                                                  \
        const float cnt = (float)max(EN - ST, 1);                          \
        const float inv = 1.0f / cnt;                                      \
        const f32x4 wv  = reinterpret_cast<const f32x4*>(weight)[CH];      \
        const f32x4 bi  = reinterpret_cast<const f32x4*>(bias)[CH];        \
        const f32x4 msc = reinterpret_cast<const f32x4*>(mean_scale)[CH];  \
        f32x4 Aa, Bb;                                                      \
        _Pragma("unroll")                                                  \
        for (int i = 0; i < 4; ++i) {                                      \
            float mean = sm[i] * inv;                                      \
            float ms   = mean * msc[i];                                    \
            float var  = fmaxf(sg[i] * inv - 2.f * mean * ms + ms * ms, 0.f); \
            float istd = rsqrtf(var + EPSV);                               \
            Aa[i] = wv[i] * istd;                                          \
            Bb[i] = bi[i] - Aa[i] * ms;                                    \
        }                                                                  \
        _Pragma("unroll")                                                  \
        for (int k = 0; k < MAXK; ++k) {                                   \
            const int r = ST + g + k * RG;                                 \
            if (r < EN)                                                    \
                __builtin_nontemporal_store(Aa * BUF[k] + Bb,              \
                                            &out4[r * CPRF + CH]);         \
        }                                                                  \
        for (int r = tail_base; r < EN; r += RG) {                         \
            f32x4 v = feat4[r * CPRF + CH];                                \
            __builtin_nontemporal_store(Aa * v + Bb, &out4[r * CPRF + CH]);\
        }                                                                  \
    }

    // prologue: stage tile 0 into bufA
    TILEINFO(base, stA, enA, chA);
    STAGE(bufA, stA, enA, chA);

    #pragma unroll 1
    for (int it = 0; it < TILES; it += 2) {
        // step even: stage it+1 -> bufB, consume bufA (parity 0)
        TILEINFO(base + it + 1, stB, enB, chB);
        STAGE(bufB, stB, enB, chB);
        CONSUME(bufA, stA, enA, chA, 0);

        // step odd: stage it+2 -> bufA (guarded), consume bufB (parity 1)
        if (it + 2 < TILES) {
            TILEINFO(base + it + 2, stA, enA, chA);
            STAGE(bufA, stA, enA, chA);
        }
        CONSUME(bufB, stB, enB, chB, 1);
    }
}

extern "C" void kernel_launch(void* const* d_in, const int* in_sizes, int n_in,
                              void* d_out, int out_size, void* d_ws, size_t ws_size,
                              hipStream_t stream) {
    const float* feat       = (const float*)d_in[0];
    const int*   seg        = (const int*)d_in[1];
    const float* weight     = (const float*)d_in[2];
    const float* bias       = (const float*)d_in[3];
    const float* mean_scale = (const float*)d_in[4];
    float* out = (float*)d_out;
    int* offs  = (int*)d_ws;   // (NSEG+1) ints

    const int N = in_sizes[0] / D;   // 1,000,000

    seg_bounds<<<(NSEG + 1 + 255) / 256, 256, 0, stream>>>(seg, offs, N);
    graphnorm_persist<<<NBLK, BLOCK, 0, stream>>>(
        feat, offs, weight, bias, mean_scale, out);
}

// Round 10
// 212.118 us; speedup vs baseline: 1.0010x; 1.0010x over previous
//
#include <hip/hip_runtime.h>

#define D 128
#define NSEG 2048
#define EPSV 1e-6f
#define BLOCK 512
#define QCH 8            // f32x4 chunks per row owned by this block (32 cols, 128 B)
#define NQ 4             // column splits per segment
#define CPRF 32          // f32x4 chunks per full row
#define RG (BLOCK/QCH)   // 64 row-groups
#define WAVES (BLOCK/64) // 8
#define MAXK 8           // buffered slots/thread: MAXK*RG = 512 rows

typedef float f32x4 __attribute__((ext_vector_type(4)));

// Tiny kernel: segment bounds (lower_bound for 0..NSEG) into d_ws.
__global__ void seg_bounds(const int* __restrict__ seg, int* __restrict__ offs, int N) {
    const int i = blockIdx.x * blockDim.x + threadIdx.x;
    if (i <= NSEG) {
        int lo = 0, hi = N;
        while (lo < hi) {
            int mid = (lo + hi) >> 1;
            if (seg[mid] < i) lo = mid + 1; else hi = mid;
        }
        offs[i] = lo;
    }
}

// R8 structure, cache-hint A/B: nontemporal on the READ stream (use-once),
// regular stores on the WRITE stream (like the 6.9 TB/s fills).
__global__ __launch_bounds__(BLOCK, 6) void graphnorm_fused(
    const float* __restrict__ feat,
    const int* __restrict__ offs,
    const float* __restrict__ weight,
    const float* __restrict__ bias,
    const float* __restrict__ mean_scale,
    float* __restrict__ out)
{
    const int bid = blockIdx.x;
    const int s = bid >> 2;        // segment
    const int q = bid & 3;         // column quarter

    const int start = offs[s];     // uniform -> scalar loads
    const int end   = offs[s + 1];

    const int t = threadIdx.x;
    const int c = t & (QCH - 1);       // chunk within slice 0..7
    const int g = t >> 3;              // row group 0..63
    const int chunk = q * QCH + c;     // chunk within full row 0..31

    __shared__ f32x4 s_sum[WAVES][QCH];
    __shared__ f32x4 s_sq[WAVES][QCH];

    const f32x4* feat4 = reinterpret_cast<const f32x4*>(feat);
    f32x4* out4 = reinterpret_cast<f32x4*>(out);

    // ---- pass 1a: bulk load into registers (static indices, nt loads) ----
    f32x4 buf[MAXK];
    #pragma unroll
    for (int k = 0; k < MAXK; ++k) {
        const int r = start + g + k * RG;
        if (r < end) buf[k] = __builtin_nontemporal_load(&feat4[r * CPRF + chunk]);
    }

    // ---- pass 1b: accumulate sum / sumsq from registers ----
    f32x4 s0 = 0.f, q0 = 0.f;
    #pragma unroll
    for (int k = 0; k < MAXK; ++k) {
        const int r = start + g + k * RG;
        if (r < end) {
            s0 += buf[k];
            q0 += buf[k] * buf[k];
        }
    }

    // tail rows beyond the register window (rare, segments > 512 rows)
    const int tail_base = start + g + MAXK * RG;
    for (int r = tail_base; r < end; r += RG) {
        f32x4 v = feat4[r * CPRF + chunk];
        s0 += v;
        q0 += v * v;
    }

    // reduce across the 8 row-groups sharing chunk c within this wave
    #pragma unroll
    for (int i = 0; i < 4; ++i) {
        s0[i] += __shfl_xor(s0[i], 8);
        s0[i] += __shfl_xor(s0[i], 16);
        s0[i] += __shfl_xor(s0[i], 32);
        q0[i] += __shfl_xor(q0[i], 8);
        q0[i] += __shfl_xor(q0[i], 16);
        q0[i] += __shfl_xor(q0[i], 32);
    }

    const int w    = t >> 6;   // wave id 0..7
    const int lane = t & 63;
    if (lane < QCH) {          // lanes 0..7 hold c == lane
        s_sum[w][lane] = s0;
        s_sq[w][lane]  = q0;
    }
    __syncthreads();

    // ---- affine coefficients, computed redundantly by every thread ----
    f32x4 sm = s_sum[0][c];
    f32x4 sg = s_sq[0][c];
    #pragma unroll
    for (int i = 1; i < WAVES; ++i) {
        sm += s_sum[i][c];
        sg += s_sq[i][c];
    }
    const float cnt = (float)max(end - start, 1);
    const float inv = 1.0f / cnt;
    const f32x4 wv  = reinterpret_cast<const f32x4*>(weight)[chunk];
    const f32x4 bi  = reinterpret_cast<const f32x4*>(bias)[chunk];
    const f32x4 msc = reinterpret_cast<const f32x4*>(mean_scale)[chunk];
    f32x4 A, B;
    #pragma unroll
    for (int i = 0; i < 4; ++i) {
        float mean = sm[i] * inv;
        float ms   = mean * msc[i];
        float var  = fmaxf(sg[i] * inv - 2.f * mean * ms + ms * ms, 0.f);
        float istd = rsqrtf(var + EPSV);
        A[i] = wv[i] * istd;
        B[i] = bi[i] - A[i] * ms;
    }

    // ---- pass 2: apply from registers, zero re-loads, REGULAR stores ----
    #pragma unroll
    for (int k = 0; k < MAXK; ++k) {
        const int r = start + g + k * RG;
        if (r < end)
            out4[r * CPRF + chunk] = A * buf[k] + B;
    }
    // tail rows: re-read via L2/L3
    for (int r = tail_base; r < end; r += RG) {
        f32x4 v = feat4[r * CPRF + chunk];
        out4[r * CPRF + chunk] = A * v + B;
    }
}

extern "C" void kernel_launch(void* const* d_in, const int* in_sizes, int n_in,
                              void* d_out, int out_size, void* d_ws, size_t ws_size,
                              hipStream_t stream) {
    const float* feat       = (const float*)d_in[0];
    const int*   seg        = (const int*)d_in[1];
    const float* weight     = (const float*)d_in[2];
    const float* bias       = (const float*)d_in[3];
    const float* mean_scale = (const float*)d_in[4];
    float* out = (float*)d_out;
    int* offs  = (int*)d_ws;   // (NSEG+1) ints

    const int N = in_sizes[0] / D;   // 1,000,000

    seg_bounds<<<(NSEG + 1 + 255) / 256, 256, 0, stream>>>(seg, offs, N);
    graphnorm_fused<<<NSEG * NQ, BLOCK, 0, stream>>>(
        feat, offs, weight, bias, mean_scale, out);
}

// Round 11
// 207.939 us; speedup vs baseline: 1.0211x; 1.0201x over previous
//
#include <hip/hip_runtime.h>

#define D 128
#define NSEG 2048
#define EPSV 1e-6f
#define BLOCK 256
#define QCH 8            // f32x4 chunks per row owned by this block (32 cols, 128 B)
#define NQ 4             // column splits per segment
#define CPRF 32          // f32x4 chunks per full row
#define RG (BLOCK/QCH)   // 32 row-groups
#define WAVES (BLOCK/64) // 4
#define MAXK 16          // buffered slots/thread: MAXK*RG = 512 rows

typedef float f32x4 __attribute__((ext_vector_type(4)));

// Tiny kernel: segment bounds (lower_bound for 0..NSEG) into d_ws.
__global__ void seg_bounds(const int* __restrict__ seg, int* __restrict__ offs, int N) {
    const int i = blockIdx.x * blockDim.x + threadIdx.x;
    if (i <= NSEG) {
        int lo = 0, hi = N;
        while (lo < hi) {
            int mid = (lo + hi) >> 1;
            if (seg[mid] < i) lo = mid + 1; else hi = mid;
        }
        offs[i] = lo;
    }
}

// Best-measured config (R6 geometry: 4 blocks/CU, 16 waves, 128 B slices,
// whole segment slice in registers -> feat read from HBM exactly once)
// + seg_bounds precompute (no per-block dependent binary-search chain).
__global__ __launch_bounds__(BLOCK, 4) void graphnorm_fused(
    const float* __restrict__ feat,
    const int* __restrict__ offs,
    const float* __restrict__ weight,
    const float* __restrict__ bias,
    const float* __restrict__ mean_scale,
    float* __restrict__ out)
{
    const int bid = blockIdx.x;
    const int s = bid >> 2;        // segment
    const int q = bid & 3;         // column quarter

    const int start = offs[s];     // uniform -> scalar loads
    const int end   = offs[s + 1];

    const int t = threadIdx.x;
    const int c = t & (QCH - 1);       // chunk within slice 0..7
    const int g = t >> 3;              // row group 0..31
    const int chunk = q * QCH + c;     // chunk within full row 0..31

    __shared__ f32x4 s_sum[WAVES][QCH];
    __shared__ f32x4 s_sq[WAVES][QCH];

    const f32x4* feat4 = reinterpret_cast<const f32x4*>(feat);
    f32x4* out4 = reinterpret_cast<f32x4*>(out);

    // ---- pass 1a: bulk load into registers (static indices) ----
    f32x4 buf[MAXK];
    #pragma unroll
    for (int k = 0; k < MAXK; ++k) {
        const int r = start + g + k * RG;
        if (r < end) buf[k] = feat4[r * CPRF + chunk];
    }

    // ---- pass 1b: accumulate sum / sumsq from registers ----
    f32x4 s0 = 0.f, q0 = 0.f;
    #pragma unroll
    for (int k = 0; k < MAXK; ++k) {
        const int r = start + g + k * RG;
        if (r < end) {
            s0 += buf[k];
            q0 += buf[k] * buf[k];
        }
    }

    // tail rows beyond the register window (rare, segments > 512 rows)
    const int tail_base = start + g + MAXK * RG;
    for (int r = tail_base; r < end; r += RG) {
        f32x4 v = feat4[r * CPRF + chunk];
        s0 += v;
        q0 += v * v;
    }

    // reduce across the 8 row-groups sharing chunk c within this wave
    #pragma unroll
    for (int i = 0; i < 4; ++i) {
        s0[i] += __shfl_xor(s0[i], 8);
        s0[i] += __shfl_xor(s0[i], 16);
        s0[i] += __shfl_xor(s0[i], 32);
        q0[i] += __shfl_xor(q0[i], 8);
        q0[i] += __shfl_xor(q0[i], 16);
        q0[i] += __shfl_xor(q0[i], 32);
    }

    const int w    = t >> 6;   // wave id 0..3
    const int lane = t & 63;
    if (lane < QCH) {          // lanes 0..7 hold c == lane
        s_sum[w][lane] = s0;
        s_sq[w][lane]  = q0;
    }
    __syncthreads();

    // ---- affine coefficients, computed redundantly by every thread ----
    f32x4 sm = s_sum[0][c];
    f32x4 sg = s_sq[0][c];
    #pragma unroll
    for (int i = 1; i < WAVES; ++i) {
        sm += s_sum[i][c];
        sg += s_sq[i][c];
    }
    const float cnt = (float)max(end - start, 1);
    const float inv = 1.0f / cnt;
    const f32x4 wv  = reinterpret_cast<const f32x4*>(weight)[chunk];
    const f32x4 bi  = reinterpret_cast<const f32x4*>(bias)[chunk];
    const f32x4 msc = reinterpret_cast<const f32x4*>(mean_scale)[chunk];
    f32x4 A, B;
    #pragma unroll
    for (int i = 0; i < 4; ++i) {
        float mean = sm[i] * inv;
        float ms   = mean * msc[i];
        float var  = fmaxf(sg[i] * inv - 2.f * mean * ms + ms * ms, 0.f);
        float istd = rsqrtf(var + EPSV);
        A[i] = wv[i] * istd;
        B[i] = bi[i] - A[i] * ms;
    }

    // ---- pass 2: apply from registers, zero re-loads, nontemporal stores ----
    #pragma unroll
    for (int k = 0; k < MAXK; ++k) {
        const int r = start + g + k * RG;
        if (r < end)
            __builtin_nontemporal_store(A * buf[k] + B, &out4[r * CPRF + chunk]);
    }
    // tail rows: re-read via L2/L3
    for (int r = tail_base; r < end; r += RG) {
        f32x4 v = feat4[r * CPRF + chunk];
        __builtin_nontemporal_store(A * v + B, &out4[r * CPRF + chunk]);
    }
}

extern "C" void kernel_launch(void* const* d_in, const int* in_sizes, int n_in,
                              void* d_out, int out_size, void* d_ws, size_t ws_size,
                              hipStream_t stream) {
    const float* feat       = (const float*)d_in[0];
    const int*   seg        = (const int*)d_in[1];
    const float* weight     = (const float*)d_in[2];
    const float* bias       = (const float*)d_in[3];
    const float* mean_scale = (const float*)d_in[4];
    float* out = (float*)d_out;
    int* offs  = (int*)d_ws;   // (NSEG+1) ints

    const int N = in_sizes[0] / D;   // 1,000,000

    seg_bounds<<<(NSEG + 1 + 255) / 256, 256, 0, stream>>>(seg, offs, N);
    graphnorm_fused<<<NSEG * NQ, BLOCK, 0, stream>>>(
        feat, offs, weight, bias, mean_scale, out);
}

// Round 12
// 201.573 us; speedup vs baseline: 1.0534x; 1.0316x over previous
//
#include <hip/hip_runtime.h>

#define D 128
#define NSEG 2048
#define EPSV 1e-6f
#define BLOCK 256
#define QCH 8            // f32x4 chunks per row owned by this block (32 columns)
#define CPRF 32          // f32x4 chunks per full row (128/4)
#define RG (BLOCK/QCH)   // 32 row-groups
#define WAVES (BLOCK/64) // 4
#define MAXK 16          // buffered slots/thread: MAXK*RG = 512 rows

typedef float f32x4 __attribute__((ext_vector_type(4)));

// Column-split: 4 blocks per segment (32 columns = 128 B slices -> one L2
// line, no cross-XCD line sharing). Whole segment slice lives in registers
// between the stats pass and the apply pass -> feat read from HBM exactly
// once; pass-2 re-read eliminated. In-kernel bounds search (a separate
// bounds kernel measured +4-8 us of serialized launch overhead).
__global__ __launch_bounds__(BLOCK, 4) void graphnorm_fused(
    const float* __restrict__ feat,
    const int* __restrict__ seg,
    const float* __restrict__ weight,
    const float* __restrict__ bias,
    const float* __restrict__ mean_scale,
    float* __restrict__ out,
    int N)
{
    const int bid = blockIdx.x;
    const int s = bid >> 2;        // segment
    const int q = bid & 3;         // column quarter
    __shared__ int s_range[2];
    __shared__ f32x4 s_sum[WAVES][QCH];
    __shared__ f32x4 s_sq[WAVES][QCH];
    __shared__ f32x4 s_a[QCH];
    __shared__ f32x4 s_b[QCH];

    const int t = threadIdx.x;

    // lower_bound for segment s (thread 0) and s+1 (thread 1)
    if (t < 2) {
        int target = s + t;
        int lo = 0, hi = N;
        while (lo < hi) {
            int mid = (lo + hi) >> 1;
            if (seg[mid] < target) lo = mid + 1; else hi = mid;
        }
        s_range[t] = lo;
    }
    __syncthreads();
    const int start = s_range[0];
    const int end   = s_range[1];

    const int c = t & (QCH - 1);       // chunk within this block's slice 0..7
    const int g = t >> 3;              // row group 0..31
    const int chunk = q * QCH + c;     // chunk within full row 0..31

    const f32x4* feat4 = reinterpret_cast<const f32x4*>(feat);
    f32x4* out4 = reinterpret_cast<f32x4*>(out);

    // ---- pass 1a: bulk load into registers (static indices) ----
    f32x4 buf[MAXK];
    #pragma unroll
    for (int k = 0; k < MAXK; ++k) {
        const int r = start + g + k * RG;
        if (r < end) buf[k] = feat4[r * CPRF + chunk];
    }

    // ---- pass 1b: accumulate sum / sumsq from registers ----
    f32x4 s0 = 0.f, q0 = 0.f;
    #pragma unroll
    for (int k = 0; k < MAXK; ++k) {
        const int r = start + g + k * RG;
        if (r < end) {
            s0 += buf[k];
            q0 += buf[k] * buf[k];
        }
    }

    // tail rows beyond the register window (rare)
    const int tail_base = start + g + MAXK * RG;
    for (int r = tail_base; r < end; r += RG) {
        f32x4 v = feat4[r * CPRF + chunk];
        s0 += v;
        q0 += v * v;
    }

    // reduce across the 8 row-groups sharing chunk c within this wave
    #pragma unroll
    for (int i = 0; i < 4; ++i) {
        s0[i] += __shfl_xor(s0[i], 8);
        s0[i] += __shfl_xor(s0[i], 16);
        s0[i] += __shfl_xor(s0[i], 32);
        q0[i] += __shfl_xor(q0[i], 8);
        q0[i] += __shfl_xor(q0[i], 16);
        q0[i] += __shfl_xor(q0[i], 32);
    }

    const int w    = t >> 6;   // wave id 0..3
    const int lane = t & 63;
    if (lane < QCH) {
        s_sum[w][lane] = s0;
        s_sq[w][lane]  = q0;
    }
    __syncthreads();

    // ---- per-column affine coefficients (threads 0..7) ----
    if (t < QCH) {
        f32x4 sm = s_sum[0][t];
        f32x4 sg = s_sq[0][t];
        #pragma unroll
        for (int i = 1; i < WAVES; ++i) {
            sm += s_sum[i][t];
            sg += s_sq[i][t];
        }
        const float cnt = (float)max(end - start, 1);
        const float inv = 1.0f / cnt;
        const int wc = q * QCH + t;
        const f32x4 wv  = reinterpret_cast<const f32x4*>(weight)[wc];
        const f32x4 bi  = reinterpret_cast<const f32x4*>(bias)[wc];
        const f32x4 msc = reinterpret_cast<const f32x4*>(mean_scale)[wc];
        f32x4 A, B;
        #pragma unroll
        for (int i = 0; i < 4; ++i) {
            float mean = sm[i] * inv;
            float ms   = mean * msc[i];
            float var  = fmaxf(sg[i] * inv - 2.f * mean * ms + ms * ms, 0.f);
            float istd = rsqrtf(var + EPSV);
            A[i] = wv[i] * istd;
            B[i] = bi[i] - A[i] * ms;
        }
        s_a[t] = A;
        s_b[t] = B;
    }
    __syncthreads();

    // ---- pass 2: apply from registers, zero re-loads, nontemporal stores ----
    const f32x4 A = s_a[c];
    const f32x4 B = s_b[c];

    #pragma unroll
    for (int k = 0; k < MAXK; ++k) {
        const int r = start + g + k * RG;
        if (r < end)
            __builtin_nontemporal_store(A * buf[k] + B, &out4[r * CPRF + chunk]);
    }
    // tail rows: re-read via L2/L3
    for (int r = tail_base; r < end; r += RG) {
        f32x4 v = feat4[r * CPRF + chunk];
        __builtin_nontemporal_store(A * v + B, &out4[r * CPRF + chunk]);
    }
}

extern "C" void kernel_launch(void* const* d_in, const int* in_sizes, int n_in,
                              void* d_out, int out_size, void* d_ws, size_t ws_size,
                              hipStream_t stream) {
    const float* feat       = (const float*)d_in[0];
    const int*   seg        = (const int*)d_in[1];
    const float* weight     = (const float*)d_in[2];
    const float* bias       = (const float*)d_in[3];
    const float* mean_scale = (const float*)d_in[4];
    float* out = (float*)d_out;

    const int N = in_sizes[0] / D;   // 1,000,000

    graphnorm_fused<<<NSEG * 4, BLOCK, 0, stream>>>(
        feat, seg, weight, bias, mean_scale, out, N);
}